// Round 8
// baseline (216.022 us; speedup 1.0000x reference)
//
#include <hip/hip_runtime.h>
#include <hip/hip_bf16.h>

typedef __attribute__((ext_vector_type(4))) float f4;
typedef __attribute__((ext_vector_type(4))) int i4;
typedef __attribute__((ext_vector_type(8))) short s8;

#define MFMA16(a,b,c) __builtin_amdgcn_mfma_f32_16x16x32_bf16((a),(b),(c),0,0,0)

static __device__ __forceinline__ unsigned short f2bf(float x){
  return __builtin_bit_cast(unsigned short, __float2bfloat16(x));
}
// B-fragment-linear index for mfma_f32_16x16x32_bf16:
// lane l holds B[k = kt*32 + (l>>4)*8 + j][col = ct*16 + (l&15)], j=0..7
__device__ __forceinline__ int fidx(int kk, int c, int nct){
  return ((((kk >> 5) * nct + (c >> 4)) << 6) + (((kk >> 3) & 3) * 16 + (c & 15))) * 8 + (kk & 7);
}

// ---------------- prep kernels ----------------
__global__ void prep1(const float* __restrict__ Ws, const float* __restrict__ Wa1,
                      const float* __restrict__ Wo,
                      unsigned short* __restrict__ Ws2f, unsigned short* __restrict__ Wof,
                      unsigned short* __restrict__ WsWa1f){
  __shared__ float wrow[256];
  int i = blockIdx.x, t = threadIdx.x;
  wrow[t] = Ws[i*256 + t];
  __syncthreads();
  float a1 = 0.f;
  for (int t2 = 0; t2 < 256; ++t2) a1 += wrow[t2] * Ws[t2*256 + t];   // Ws2 = Ws@Ws
  Ws2f[fidx(i, t, 16)] = f2bf(a1);
  Wof[fidx(i, t, 16)]  = f2bf(Wo[i*256 + t]);
  if (t < 32){
    float a2 = 0.f;
    for (int t2 = 0; t2 < 256; ++t2) a2 += wrow[t2] * Wa1[t2*32 + t]; // WsWa1 = Ws@Wa1
    WsWa1f[fidx(i, t, 2)] = f2bf(a2);
  }
}

// 64 blocks x 256 (was 1 block -- serialized on one CU)
__global__ void prep2(const float* __restrict__ Wp2, const float* __restrict__ Wa2,
                      const float* __restrict__ Wa1, const float* __restrict__ bp2,
                      const float* __restrict__ ba1,
                      unsigned short* __restrict__ Wp2f, unsigned short* __restrict__ Wa2f,
                      unsigned short* __restrict__ Wp2Wa1f, float* __restrict__ bh){
  int gid = blockIdx.x * 256 + threadIdx.x;   // 0..16383
  if (gid < 8192){
    int kk = gid >> 8, c = gid & 255;
    Wp2f[fidx(kk, c, 16)] = f2bf(Wp2[gid]);
  } else {
    int g = gid - 8192; int kk = g >> 8, c = g & 255;
    Wa2f[fidx(kk, c, 16)] = f2bf(Wa2[g]);
  }
  if (gid < 1024){                     // Wp2Wa1 = Wp2@Wa1 [32][32]
    int h1 = gid >> 5, h2 = gid & 31;
    float a = 0.f;
    for (int c = 0; c < 256; ++c) a += Wp2[h1*256 + c] * Wa1[c*32 + h2];
    Wp2Wa1f[fidx(h1, h2, 2)] = f2bf(a);
  }
  if (gid < 32){                       // bh = bp2@Wa1 + ba1
    float a = ba1[gid];
    for (int c = 0; c < 256; ++c) a += bp2[c] * Wa1[c*32 + gid];
    bh[gid] = a;
  }
}

// ---------------- main kernel: k in regs, weights LDS-dbuf, x -> global ----------------
// Block = 4 n-rows, wave w <-> n for the WHOLE kernel (no column split, no kA).
// Weight tiles {Ws2[ct] 8K, Wp2[ct] 1K, Wa2[ct] 1K} double-buffered in LDS,
// shared by all 4 waves; T14 async-STAGE (load-early / ds_write-late / barrier).
__global__ __launch_bounds__(256, 4) void attn_x2(
  const float* __restrict__ q, const float* __restrict__ k,
  const float* __restrict__ pos, const int* __restrict__ mask,
  const float* __restrict__ Wp1, const float* __restrict__ bp1,
  const float* __restrict__ bp2, const float* __restrict__ bh,
  const unsigned short* __restrict__ Ws2f, const unsigned short* __restrict__ WsWa1f,
  const unsigned short* __restrict__ Wp2f, const unsigned short* __restrict__ Wa2f,
  const unsigned short* __restrict__ Wp2Wa1f,
  unsigned short* __restrict__ xbuf)
{
  __shared__ unsigned short wS[2][5120]; // 20 KB: [buf][chunk0..9 x 512] (Ws2 kt0..7, Wp2, Wa2)
  __shared__ unsigned short hB[2048];    // 4 KB: per-wave 1 KB C->A bounce

  const int t = threadIdx.x;
  const int lane = t & 63;
  const int w = t >> 6;
  const int lg = lane >> 4;
  const int lr = lane & 15;
  const int bn0 = blockIdx.x * 4;
  const int n0 = bn0 + w;              // this wave's n-row
  const f4 z4 = {0.f, 0.f, 0.f, 0.f};

  // ---- issue ct=0 weight stage loads FIRST (latency hides under phase B)
  s8 i0 = *(const s8*)(Ws2f + (((size_t)w * 16) * 64 + lane) * 8);         // chunk kt=w
  s8 i1 = *(const s8*)(Ws2f + (((size_t)(w + 4) * 16) * 64 + lane) * 8);   // chunk kt=w+4
  s8 i2 = {0,0,0,0,0,0,0,0};
  if (w == 0) i2 = *(const s8*)(Wp2f + (size_t)lane * 8);
  if (w == 1) i2 = *(const s8*)(Wa2f + (size_t)lane * 8);

  // ---- Phase B: per-kt {k,q loads, convert, kh MFMAs}; kfrag stays in regs
  const float* krow = k + (size_t)n0 * 4096 + (size_t)lr * 256;
  const float* qrow = q + (size_t)n0 * 256;
  const unsigned short* wa1b = WsWa1f + (size_t)lane * 8;
  s8 kfrag[8];
  f4 khac[2] = {z4, z4};
  #pragma unroll
  for (int kt = 0; kt < 8; ++kt){
    int c0 = kt * 32 + lg * 8;
    f4 ka = *(const f4*)(krow + c0);
    f4 kb = *(const f4*)(krow + c0 + 4);
    f4 qa = *(const f4*)(qrow + c0);
    f4 qb = *(const f4*)(qrow + c0 + 4);
    s8 kf, mf;
    #pragma unroll
    for (int j = 0; j < 4; ++j){
      kf[j]     = (short)f2bf(ka[j]);
      kf[4 + j] = (short)f2bf(kb[j]);
      mf[j]     = (short)f2bf(ka[j] - qa[j]);
      mf[4 + j] = (short)f2bf(kb[j] - qb[j]);
    }
    kfrag[kt] = kf;
    khac[0] = MFMA16(mf, *(const s8*)(wa1b + (size_t)(kt * 2 + 0) * 512), khac[0]);
    khac[1] = MFMA16(mf, *(const s8*)(wa1b + (size_t)(kt * 2 + 1) * 512), khac[1]);
  }

  // pos-MLP per-lane directly in A-frag layout
  s8 phfrag;
  {
    f4 pv = *(const f4*)(pos + (size_t)n0 * 64 + (size_t)lr * 4);
    f4 h0 = *(const f4*)(bp1 + lg * 8);
    f4 h1 = *(const f4*)(bp1 + lg * 8 + 4);
    #pragma unroll
    for (int p = 0; p < 4; ++p){
      f4 w0 = *(const f4*)(Wp1 + p * 32 + lg * 8);
      f4 w1 = *(const f4*)(Wp1 + p * 32 + lg * 8 + 4);
      #pragma unroll
      for (int j = 0; j < 4; ++j){ h0[j] += pv[p] * w0[j]; h1[j] += pv[p] * w1[j]; }
    }
    #pragma unroll
    for (int j = 0; j < 4; ++j){
      phfrag[j]     = (short)f2bf(fmaxf(h0[j], 0.f));
      phfrag[4 + j] = (short)f2bf(fmaxf(h1[j], 0.f));
    }
  }

  // khac += ph@Wp2Wa1
  {
    const unsigned short* wpwb = Wp2Wa1f + (size_t)lane * 8;
    khac[0] = MFMA16(phfrag, *(const s8*)(wpwb), khac[0]);
    khac[1] = MFMA16(phfrag, *(const s8*)(wpwb + 512), khac[1]);
  }

  // h = relu(khac + bh): C-layout -> A-frag via per-wave LDS bounce (same-wave, no barrier)
  unsigned short* hw = hB + w * 512;
  #pragma unroll
  for (int ct2 = 0; ct2 < 2; ++ct2){
    float bhc = bh[ct2 * 16 + lr];
    #pragma unroll
    for (int r = 0; r < 4; ++r){
      int m = lg * 4 + r, col = ct2 * 16 + lr;
      hw[((col >> 3) * 16 + m) * 8 + (col & 7)] = f2bf(fmaxf(khac[ct2][r] + bhc, 0.f));
    }
  }
  s8 hfrag = *(const s8*)(hw + lane * 8);

  // write ct=0 stage into buf0, barrier
  {
    unsigned short* wb = &wS[0][0];
    *(s8*)(wb + ((size_t)w * 64 + lane) * 8) = i0;
    *(s8*)(wb + ((size_t)(w + 4) * 64 + lane) * 8) = i1;
    if (w < 2) *(s8*)(wb + ((size_t)(8 + w) * 64 + lane) * 8) = i2;
  }
  __syncthreads();

  // ---- Phase E: ct loop over 16 column-tiles; weights from LDS dbuf
  i4 mv = *(const i4*)(mask + (size_t)n0 * 16 + lg * 4);
  #pragma unroll 1
  for (int ct = 0; ct < 16; ++ct){
    // prefetch ct+1 weight tiles (issue loads now, write after compute)
    s8 st0 = {0,0,0,0,0,0,0,0}, st1 = st0, st2 = st0;
    if (ct < 15){
      int c1 = ct + 1;
      st0 = *(const s8*)(Ws2f + (((size_t)w * 16 + c1) * 64 + lane) * 8);
      st1 = *(const s8*)(Ws2f + (((size_t)(w + 4) * 16 + c1) * 64 + lane) * 8);
      if (w == 0) st2 = *(const s8*)(Wp2f + ((size_t)c1 * 64 + lane) * 8);
      if (w == 1) st2 = *(const s8*)(Wa2f + ((size_t)c1 * 64 + lane) * 8);
    }
    const unsigned short* wcur = &wS[ct & 1][0];
    // v = k @ Ws2[:,ct] : two independent 4-deep chains
    f4 va = z4, vb = z4;
    #pragma unroll
    for (int kt = 0; kt < 4; ++kt){
      s8 b0 = *(const s8*)(wcur + ((kt    ) * 64 + lane) * 8);
      s8 b1 = *(const s8*)(wcur + ((kt + 4) * 64 + lane) * 8);
      va = MFMA16(kfrag[kt],     b0, va);
      vb = MFMA16(kfrag[kt + 4], b1, vb);
    }
    f4 pfv = MFMA16(phfrag, *(const s8*)(wcur + (8 * 64 + lane) * 8), z4);
    f4 aav = MFMA16(hfrag,  *(const s8*)(wcur + (9 * 64 + lane) * 8), z4);
    // masked softmax over m for this wave's n
    float bp2c = bp2[ct * 16 + lr];
    float lg0 = mv[0] ? aav[0] : -1e9f;
    float lg1 = mv[1] ? aav[1] : -1e9f;
    float lg2 = mv[2] ? aav[2] : -1e9f;
    float lg3 = mv[3] ? aav[3] : -1e9f;
    float mx = fmaxf(fmaxf(lg0, lg1), fmaxf(lg2, lg3));
    mx = fmaxf(mx, __shfl_xor(mx, 16));
    mx = fmaxf(mx, __shfl_xor(mx, 32));
    float p0 = __expf(lg0 - mx), p1 = __expf(lg1 - mx);
    float p2 = __expf(lg2 - mx), p3 = __expf(lg3 - mx);
    float den = p0 + p1 + p2 + p3;
    float num = p0 * (va[0] + vb[0] + pfv[0] + bp2c)
              + p1 * (va[1] + vb[1] + pfv[1] + bp2c)
              + p2 * (va[2] + vb[2] + pfv[2] + bp2c)
              + p3 * (va[3] + vb[3] + pfv[3] + bp2c);
    den += __shfl_xor(den, 16); den += __shfl_xor(den, 32);
    num += __shfl_xor(num, 16); num += __shfl_xor(num, 32);
    // write next stage + barrier
    if (ct < 15){
      unsigned short* wnx = &wS[(ct + 1) & 1][0];
      *(s8*)(wnx + ((size_t)w * 64 + lane) * 8) = st0;
      *(s8*)(wnx + ((size_t)(w + 4) * 64 + lane) * 8) = st1;
      if (w < 2) *(s8*)(wnx + ((size_t)(8 + w) * 64 + lane) * 8) = st2;
    }
    if (lane < 16)
      xbuf[(size_t)n0 * 256 + ct * 16 + lr] = f2bf(__fdividef(num, den));
    if (ct < 15) __syncthreads();
  }
}

// ---------------- proj kernel: out = x @ Wo + bo ----------------
__global__ __launch_bounds__(128, 4) void proj(
  const unsigned short* __restrict__ xbuf, const unsigned short* __restrict__ Wof,
  const float* __restrict__ bo, float* __restrict__ out)
{
  const int t = threadIdx.x;
  const int lane = t & 63;
  const int w = t >> 6;
  const int lg = lane >> 4;
  const int lr = lane & 15;
  const int n0 = blockIdx.x * 32 + w * 16;
  const f4 z4 = {0.f, 0.f, 0.f, 0.f};
  const unsigned short* xr = xbuf + (size_t)(n0 + lr) * 256;
  const unsigned short* wob = Wof + (size_t)lane * 8;
  #pragma unroll
  for (int p = 0; p < 4; ++p){
    f4 oac[4] = {z4, z4, z4, z4};
    #pragma unroll
    for (int kt = 0; kt < 8; ++kt){
      s8 xf = *(const s8*)(xr + kt * 32 + lg * 8);
      #pragma unroll
      for (int ci = 0; ci < 4; ++ci)
        oac[ci] = MFMA16(xf, *(const s8*)(wob + (size_t)(kt * 16 + p * 4 + ci) * 512), oac[ci]);
    }
    #pragma unroll
    for (int ci = 0; ci < 4; ++ci){
      int c = (p * 4 + ci) * 16 + lr;
      float bov = bo[c];
      #pragma unroll
      for (int r = 0; r < 4; ++r)
        out[(size_t)(n0 + lg * 4 + r) * 256 + c] = oac[ci][r] + bov;
    }
  }
}

// ---------------- fallback monolithic kernel (R4, proven) ----------------
__global__ __launch_bounds__(256, 4) void attn_mono(
  const float* __restrict__ q, const float* __restrict__ k,
  const float* __restrict__ pos, const int* __restrict__ mask,
  const float* __restrict__ Wp1, const float* __restrict__ bp1,
  const float* __restrict__ bp2, const float* __restrict__ bo,
  const float* __restrict__ bh,
  const unsigned short* __restrict__ Ws2f, const unsigned short* __restrict__ WsWa1f,
  const unsigned short* __restrict__ Wp2f, const unsigned short* __restrict__ Wa2f,
  const unsigned short* __restrict__ Wp2Wa1f, const unsigned short* __restrict__ Wof,
  float* __restrict__ out)
{
  __shared__ unsigned short kA[16384];
  __shared__ unsigned short phL[2048];
  __shared__ unsigned short hL[2048];
  __shared__ unsigned short xT[4096];

  const int t = threadIdx.x;
  const int lane = t & 63;
  const int w = t >> 6;
  const int lg = lane >> 4;
  const int lr = lane & 15;
  const int bn0 = blockIdx.x * 4;
  const int n0 = bn0 + w;
  const f4 z4 = {0.f, 0.f, 0.f, 0.f};

  const float* krow = k + (size_t)n0 * 4096 + (size_t)lr * 256;
  const float* qrow = q + (size_t)n0 * 256;
  const unsigned short* wa1b = WsWa1f + (size_t)lane * 8;
  f4 khac[2] = {z4, z4};
  #pragma unroll
  for (int kt = 0; kt < 8; ++kt){
    int c0 = kt * 32 + lg * 8;
    f4 ka = *(const f4*)(krow + c0);
    f4 kb = *(const f4*)(krow + c0 + 4);
    f4 qa = *(const f4*)(qrow + c0);
    f4 qb = *(const f4*)(qrow + c0 + 4);
    s8 kf, mf;
    #pragma unroll
    for (int j = 0; j < 4; ++j){
      kf[j]     = (short)f2bf(ka[j]);
      kf[4 + j] = (short)f2bf(kb[j]);
      mf[j]     = (short)f2bf(ka[j] - qa[j]);
      mf[4 + j] = (short)f2bf(kb[j] - qb[j]);
    }
    *(s8*)(kA + ((w * 8 + kt) * 64 + lane) * 8) = kf;
    khac[0] = MFMA16(mf, *(const s8*)(wa1b + (size_t)(kt * 2 + 0) * 512), khac[0]);
    khac[1] = MFMA16(mf, *(const s8*)(wa1b + (size_t)(kt * 2 + 1) * 512), khac[1]);
  }
  s8 phfrag;
  {
    f4 pv = *(const f4*)(pos + (size_t)n0 * 64 + (size_t)lr * 4);
    f4 h0 = *(const f4*)(bp1 + lg * 8);
    f4 h1 = *(const f4*)(bp1 + lg * 8 + 4);
    #pragma unroll
    for (int p = 0; p < 4; ++p){
      f4 w0 = *(const f4*)(Wp1 + p * 32 + lg * 8);
      f4 w1 = *(const f4*)(Wp1 + p * 32 + lg * 8 + 4);
      #pragma unroll
      for (int j = 0; j < 4; ++j){ h0[j] += pv[p] * w0[j]; h1[j] += pv[p] * w1[j]; }
    }
    #pragma unroll
    for (int j = 0; j < 4; ++j){
      phfrag[j]     = (short)f2bf(fmaxf(h0[j], 0.f));
      phfrag[4 + j] = (short)f2bf(fmaxf(h1[j], 0.f));
    }
  }
  *(s8*)(phL + (w * 64 + lane) * 8) = phfrag;
  {
    const unsigned short* wpwb = Wp2Wa1f + (size_t)lane * 8;
    khac[0] = MFMA16(phfrag, *(const s8*)(wpwb), khac[0]);
    khac[1] = MFMA16(phfrag, *(const s8*)(wpwb + 512), khac[1]);
  }
  #pragma unroll
  for (int ct2 = 0; ct2 < 2; ++ct2){
    float bhc = bh[ct2 * 16 + lr];
    #pragma unroll
    for (int r = 0; r < 4; ++r){
      int m = lg * 4 + r, col = ct2 * 16 + lr;
      hL[w * 512 + ((col >> 3) * 16 + m) * 8 + (col & 7)] = f2bf(fmaxf(khac[ct2][r] + bhc, 0.f));
    }
  }
  __syncthreads();

  const unsigned short* ws2b = Ws2f + (size_t)lane * 8;
  const unsigned short* wp2b = Wp2f + (size_t)lane * 8;
  const unsigned short* wa2b = Wa2f + (size_t)lane * 8;
  #pragma unroll
  for (int ci = 0; ci < 4; ++ci){
    int ct = w * 4 + ci;
    f4 vacc[4] = {z4, z4, z4, z4};
    #pragma unroll
    for (int kt = 0; kt < 8; ++kt){
      s8 bw = *(const s8*)(ws2b + (size_t)(kt * 16 + ct) * 512);
      #pragma unroll
      for (int n = 0; n < 4; ++n){
        s8 af = *(const s8*)(kA + ((n * 8 + kt) * 64 + lane) * 8);
        vacc[n] = MFMA16(af, bw, vacc[n]);
      }
    }
    s8 bp = *(const s8*)(wp2b + (size_t)ct * 512);
    s8 ba = *(const s8*)(wa2b + (size_t)ct * 512);
    f4 pf[4], aa[4];
    #pragma unroll
    for (int n = 0; n < 4; ++n){
      s8 pfr = *(const s8*)(phL + (n * 64 + lane) * 8);
      s8 hfr = *(const s8*)(hL + (n * 64 + lane) * 8);
      pf[n] = MFMA16(pfr, bp, z4);
      aa[n] = MFMA16(hfr, ba, z4);
    }
    float bp2c = bp2[ct * 16 + lr];
    #pragma unroll
    for (int n = 0; n < 4; ++n){
      i4 mv = *(const i4*)(mask + (size_t)(bn0 + n) * 16 + lg * 4);
      float lg0 = mv[0] ? aa[n][0] : -1e9f;
      float lg1 = mv[1] ? aa[n][1] : -1e9f;
      float lg2 = mv[2] ? aa[n][2] : -1e9f;
      float lg3 = mv[3] ? aa[n][3] : -1e9f;
      float mx = fmaxf(fmaxf(lg0, lg1), fmaxf(lg2, lg3));
      mx = fmaxf(mx, __shfl_xor(mx, 16));
      mx = fmaxf(mx, __shfl_xor(mx, 32));
      float p0 = __expf(lg0 - mx), p1 = __expf(lg1 - mx);
      float p2 = __expf(lg2 - mx), p3 = __expf(lg3 - mx);
      float den = p0 + p1 + p2 + p3;
      float num = p0 * (vacc[n][0] + pf[n][0] + bp2c)
                + p1 * (vacc[n][1] + pf[n][1] + bp2c)
                + p2 * (vacc[n][2] + pf[n][2] + bp2c)
                + p3 * (vacc[n][3] + pf[n][3] + bp2c);
      den += __shfl_xor(den, 16); den += __shfl_xor(den, 32);
      num += __shfl_xor(num, 16); num += __shfl_xor(num, 32);
      if (lane < 16){
        int c = ct * 16 + lr;
        xT[((c >> 5) * 64 + ((c >> 3) & 3) * 16 + n) * 8 + (c & 7)] = f2bf(__fdividef(num, den));
      }
    }
  }
  __syncthreads();

  f4 oac[4] = {z4, z4, z4, z4};
  const unsigned short* wob = Wof + (size_t)lane * 8;
  #pragma unroll
  for (int kt = 0; kt < 8; ++kt){
    s8 xf = *(const s8*)(xT + (kt * 64 + lane) * 8);
    #pragma unroll
    for (int ci = 0; ci < 4; ++ci)
      oac[ci] = MFMA16(xf, *(const s8*)(wob + (size_t)(kt * 16 + w * 4 + ci) * 512), oac[ci]);
  }
  if (lane < 16){
    #pragma unroll
    for (int ci = 0; ci < 4; ++ci){
      int c = (w * 4 + ci) * 16 + lr;
      float bov = bo[c];
      #pragma unroll
      for (int r = 0; r < 4; ++r)
        out[(size_t)(bn0 + r) * 256 + c] = oac[ci][r] + bov;
    }
  }
}

extern "C" void kernel_launch(void* const* d_in, const int* in_sizes, int n_in,
                              void* d_out, int out_size, void* d_ws, size_t ws_size,
                              hipStream_t stream) {
  (void)in_sizes; (void)n_in; (void)out_size;
  const float* q   = (const float*)d_in[0];
  const float* k   = (const float*)d_in[1];
  const float* pos = (const float*)d_in[2];
  const int*   msk = (const int*)d_in[3];
  const float* Ws  = (const float*)d_in[4];
  const float* Wp1 = (const float*)d_in[5];
  const float* bp1 = (const float*)d_in[6];
  const float* Wp2 = (const float*)d_in[7];
  const float* bp2 = (const float*)d_in[8];
  const float* Wa1 = (const float*)d_in[9];
  const float* ba1 = (const float*)d_in[10];
  const float* Wa2 = (const float*)d_in[11];
  // d_in[12] = ba2: constant along softmax axis -> mathematically a no-op
  const float* Wo  = (const float*)d_in[13];
  const float* bo  = (const float*)d_in[14];

  if (ws_size < 313472) return;
  char* ws = (char*)d_ws;
  unsigned short* Ws2f    = (unsigned short*)(ws + 0);       // 131072 B
  unsigned short* Wof     = (unsigned short*)(ws + 131072);  // 131072 B
  unsigned short* WsWa1f  = (unsigned short*)(ws + 262144);  // 16384 B
  unsigned short* Wp2f    = (unsigned short*)(ws + 278528);  // 16384 B
  unsigned short* Wa2f    = (unsigned short*)(ws + 294912);  // 16384 B
  unsigned short* Wp2Wa1f = (unsigned short*)(ws + 311296);  // 2048 B
  float*          bh      = (float*)(ws + 313344);           // 128 B
  unsigned short* xbuf    = (unsigned short*)(ws + 313472);  // 8388608 B

  prep1<<<dim3(256), dim3(256), 0, stream>>>(Ws, Wa1, Wo, Ws2f, Wof, WsWa1f);
  prep2<<<dim3(64), dim3(256), 0, stream>>>(Wp2, Wa2, Wa1, bp2, ba1, Wp2f, Wa2f, Wp2Wa1f, bh);

  if (ws_size >= 313472 + 8388608) {
    attn_x2<<<dim3(4096), dim3(256), 0, stream>>>(q, k, pos, msk, Wp1, bp1, bp2, bh,
                                                  Ws2f, WsWa1f, Wp2f, Wa2f, Wp2Wa1f, xbuf);
    proj<<<dim3(512), dim3(128), 0, stream>>>(xbuf, Wof, bo, (float*)d_out);
  } else {
    attn_mono<<<dim3(4096), dim3(256), 0, stream>>>(q, k, pos, msk, Wp1, bp1, bp2, bo, bh,
                                                    Ws2f, WsWa1f, Wp2f, Wa2f, Wp2Wa1f, Wof,
                                                    (float*)d_out);
  }
}

// Round 9
// 184.238 us; speedup vs baseline: 1.1725x; 1.1725x over previous
//
#include <hip/hip_runtime.h>
#include <hip/hip_bf16.h>

typedef __attribute__((ext_vector_type(4))) float f4;
typedef __attribute__((ext_vector_type(4))) int i4;
typedef __attribute__((ext_vector_type(8))) short s8;

#define MFMA16(a,b,c) __builtin_amdgcn_mfma_f32_16x16x32_bf16((a),(b),(c),0,0,0)

static __device__ __forceinline__ unsigned short f2bf(float x){
  return __builtin_bit_cast(unsigned short, __float2bfloat16(x));
}
// B-fragment-linear index for mfma_f32_16x16x32_bf16:
// lane l holds B[k = kt*32 + (l>>4)*8 + j][col = ct*16 + (l&15)], j=0..7
__device__ __forceinline__ int fidx(int kk, int c, int nct){
  return ((((kk >> 5) * nct + (c >> 4)) << 6) + (((kk >> 3) & 3) * 16 + (c & 15))) * 8 + (kk & 7);
}

// ---------------- prep kernels ----------------
__global__ void prep1(const float* __restrict__ Ws, const float* __restrict__ Wa1,
                      const float* __restrict__ Wo,
                      unsigned short* __restrict__ Ws2f, unsigned short* __restrict__ Wof,
                      unsigned short* __restrict__ WsWa1f){
  __shared__ float wrow[256];
  int i = blockIdx.x, t = threadIdx.x;
  wrow[t] = Ws[i*256 + t];
  __syncthreads();
  float a1 = 0.f;
  for (int t2 = 0; t2 < 256; ++t2) a1 += wrow[t2] * Ws[t2*256 + t];   // Ws2 = Ws@Ws
  Ws2f[fidx(i, t, 16)] = f2bf(a1);
  Wof[fidx(i, t, 16)]  = f2bf(Wo[i*256 + t]);
  if (t < 32){
    float a2 = 0.f;
    for (int t2 = 0; t2 < 256; ++t2) a2 += wrow[t2] * Wa1[t2*32 + t]; // WsWa1 = Ws@Wa1
    WsWa1f[fidx(i, t, 2)] = f2bf(a2);
  }
}

// 64 blocks x 256 threads (parallelized -- single-block version serialized on one CU)
__global__ void prep2(const float* __restrict__ Wp2, const float* __restrict__ Wa2,
                      const float* __restrict__ Wa1, const float* __restrict__ bp2,
                      const float* __restrict__ ba1,
                      unsigned short* __restrict__ Wp2f, unsigned short* __restrict__ Wa2f,
                      unsigned short* __restrict__ Wp2Wa1f, float* __restrict__ bh){
  int gid = blockIdx.x * 256 + threadIdx.x;   // 0..16383
  if (gid < 8192){
    int kk = gid >> 8, c = gid & 255;
    Wp2f[fidx(kk, c, 16)] = f2bf(Wp2[gid]);
  } else {
    int g = gid - 8192; int kk = g >> 8, c = g & 255;
    Wa2f[fidx(kk, c, 16)] = f2bf(Wa2[g]);
  }
  if (gid < 1024){                     // Wp2Wa1 = Wp2@Wa1 [32][32]
    int h1 = gid >> 5, h2 = gid & 31;
    float a = 0.f;
    for (int c = 0; c < 256; ++c) a += Wp2[h1*256 + c] * Wa1[c*32 + h2];
    Wp2Wa1f[fidx(h1, h2, 2)] = f2bf(a);
  }
  if (gid < 32){                       // bh = bp2@Wa1 + ba1
    float a = ba1[gid];
    for (int c = 0; c < 256; ++c) a += bp2[c] * Wa1[c*32 + gid];
    bh[gid] = a;
  }
}

// ---------------- main kernel: phases B..E, x -> global bf16 ----------------
// Block = 4 n-rows. Phase B row-split (wave w <-> n w), phase E column-split
// (wave w <-> cols [64w,64w+64)) with ci-PAIRING: one pass over kA feeds two
// ct columns -> kA ds_reads halved (128->64 per wave). ONE barrier.
// R5/R6/R8 lesson: no persistent register arrays across phases (spill).
__global__ __launch_bounds__(256, 4) void attn_x(
  const float* __restrict__ q, const float* __restrict__ k,
  const float* __restrict__ pos, const int* __restrict__ mask,
  const float* __restrict__ Wp1, const float* __restrict__ bp1,
  const float* __restrict__ bp2, const float* __restrict__ bh,
  const unsigned short* __restrict__ Ws2f, const unsigned short* __restrict__ WsWa1f,
  const unsigned short* __restrict__ Wp2f, const unsigned short* __restrict__ Wa2f,
  const unsigned short* __restrict__ Wp2Wa1f,
  unsigned short* __restrict__ xbuf)
{
  __shared__ unsigned short kA[16384];  // 32 KB: [n][kt][lane][8] bf16 A-frags of k
  __shared__ unsigned short phL[2048];  // 4 KB:  [n][lane][8] pos-hidden A-frags
  __shared__ unsigned short hL[2048];   // 4 KB:  [n][lane][8] attn-hidden A-frags

  const int t = threadIdx.x;
  const int lane = t & 63;
  const int w = t >> 6;
  const int lg = lane >> 4;
  const int lr = lane & 15;
  const int bn0 = blockIdx.x * 4;
  const int n0 = bn0 + w;
  const f4 z4 = {0.f, 0.f, 0.f, 0.f};

  // ---- Phase B: per-kt {k,q loads, convert, kA write, kh MFMAs}
  const float* krow = k + (size_t)n0 * 4096 + (size_t)lr * 256;
  const float* qrow = q + (size_t)n0 * 256;
  const unsigned short* wa1b = WsWa1f + (size_t)lane * 8;
  f4 khac[2] = {z4, z4};
  #pragma unroll
  for (int kt = 0; kt < 8; ++kt){
    int c0 = kt * 32 + lg * 8;
    f4 ka = *(const f4*)(krow + c0);
    f4 kb = *(const f4*)(krow + c0 + 4);
    f4 qa = *(const f4*)(qrow + c0);
    f4 qb = *(const f4*)(qrow + c0 + 4);
    s8 kf, mf;
    #pragma unroll
    for (int j = 0; j < 4; ++j){
      kf[j]     = (short)f2bf(ka[j]);
      kf[4 + j] = (short)f2bf(kb[j]);
      mf[j]     = (short)f2bf(ka[j] - qa[j]);
      mf[4 + j] = (short)f2bf(kb[j] - qb[j]);
    }
    *(s8*)(kA + ((w * 8 + kt) * 64 + lane) * 8) = kf;
    khac[0] = MFMA16(mf, *(const s8*)(wa1b + (size_t)(kt * 2 + 0) * 512), khac[0]);
    khac[1] = MFMA16(mf, *(const s8*)(wa1b + (size_t)(kt * 2 + 1) * 512), khac[1]);
  }

  // pos-MLP per-lane directly in A-frag layout
  s8 phfrag;
  {
    f4 pv = *(const f4*)(pos + (size_t)n0 * 64 + (size_t)lr * 4);
    f4 h0 = *(const f4*)(bp1 + lg * 8);
    f4 h1 = *(const f4*)(bp1 + lg * 8 + 4);
    #pragma unroll
    for (int p = 0; p < 4; ++p){
      f4 w0 = *(const f4*)(Wp1 + p * 32 + lg * 8);
      f4 w1 = *(const f4*)(Wp1 + p * 32 + lg * 8 + 4);
      #pragma unroll
      for (int j = 0; j < 4; ++j){ h0[j] += pv[p] * w0[j]; h1[j] += pv[p] * w1[j]; }
    }
    #pragma unroll
    for (int j = 0; j < 4; ++j){
      phfrag[j]     = (short)f2bf(fmaxf(h0[j], 0.f));
      phfrag[4 + j] = (short)f2bf(fmaxf(h1[j], 0.f));
    }
  }
  *(s8*)(phL + (w * 64 + lane) * 8) = phfrag;

  // khac += ph@Wp2Wa1
  {
    const unsigned short* wpwb = Wp2Wa1f + (size_t)lane * 8;
    khac[0] = MFMA16(phfrag, *(const s8*)(wpwb), khac[0]);
    khac[1] = MFMA16(phfrag, *(const s8*)(wpwb + 512), khac[1]);
  }

  // h = relu(khac + bh) scattered into hL A-frag slots
  #pragma unroll
  for (int ct2 = 0; ct2 < 2; ++ct2){
    float bhc = bh[ct2 * 16 + lr];
    #pragma unroll
    for (int r = 0; r < 4; ++r){
      int m = lg * 4 + r, col = ct2 * 16 + lr;
      hL[w * 512 + ((col >> 3) * 16 + m) * 8 + (col & 7)] = f2bf(fmaxf(khac[ct2][r] + bhc, 0.f));
    }
  }
  __syncthreads();

  // ---- Phase E: column-split with ci-pairs. Wave w owns ct = 4w..4w+3.
  const unsigned short* ws2b = Ws2f + (size_t)lane * 8;
  const unsigned short* wp2b = Wp2f + (size_t)lane * 8;
  const unsigned short* wa2b = Wa2f + (size_t)lane * 8;

  auto epilogue = [&](const f4* vv, int ct){
    s8 bp = *(const s8*)(wp2b + (size_t)ct * 512);
    s8 ba = *(const s8*)(wa2b + (size_t)ct * 512);
    f4 pf[4], aa[4];
    #pragma unroll
    for (int n = 0; n < 4; ++n){
      s8 pfr = *(const s8*)(phL + (n * 64 + lane) * 8);
      s8 hfr = *(const s8*)(hL + (n * 64 + lane) * 8);
      pf[n] = MFMA16(pfr, bp, z4);
      aa[n] = MFMA16(hfr, ba, z4);
    }
    float bp2c = bp2[ct * 16 + lr];
    #pragma unroll
    for (int n = 0; n < 4; ++n){
      i4 mv = *(const i4*)(mask + (size_t)(bn0 + n) * 16 + lg * 4);
      float lg0 = mv[0] ? aa[n][0] : -1e9f;
      float lg1 = mv[1] ? aa[n][1] : -1e9f;
      float lg2 = mv[2] ? aa[n][2] : -1e9f;
      float lg3 = mv[3] ? aa[n][3] : -1e9f;
      float mx = fmaxf(fmaxf(lg0, lg1), fmaxf(lg2, lg3));
      mx = fmaxf(mx, __shfl_xor(mx, 16));
      mx = fmaxf(mx, __shfl_xor(mx, 32));
      float p0 = __expf(lg0 - mx), p1 = __expf(lg1 - mx);
      float p2 = __expf(lg2 - mx), p3 = __expf(lg3 - mx);
      float den = p0 + p1 + p2 + p3;
      float num = p0 * (vv[n][0] + pf[n][0] + bp2c)
                + p1 * (vv[n][1] + pf[n][1] + bp2c)
                + p2 * (vv[n][2] + pf[n][2] + bp2c)
                + p3 * (vv[n][3] + pf[n][3] + bp2c);
      den += __shfl_xor(den, 16); den += __shfl_xor(den, 32);
      num += __shfl_xor(num, 16); num += __shfl_xor(num, 32);
      if (lane < 16)
        xbuf[(size_t)(bn0 + n) * 256 + ct * 16 + lr] = f2bf(__fdividef(num, den));
    }
  };

  #pragma unroll
  for (int cp = 0; cp < 2; ++cp){
    const int ct0 = w * 4 + cp * 2;
    const int ct1 = ct0 + 1;
    f4 v0[4] = {z4, z4, z4, z4};
    f4 v1[4] = {z4, z4, z4, z4};
    #pragma unroll
    for (int kt = 0; kt < 8; ++kt){
      s8 b0 = *(const s8*)(ws2b + (size_t)(kt * 16 + ct0) * 512);
      s8 b1 = *(const s8*)(ws2b + (size_t)(kt * 16 + ct1) * 512);
      #pragma unroll
      for (int n = 0; n < 4; ++n){
        s8 af = *(const s8*)(kA + ((n * 8 + kt) * 64 + lane) * 8);
        v0[n] = MFMA16(af, b0, v0[n]);
        v1[n] = MFMA16(af, b1, v1[n]);
      }
    }
    epilogue(v0, ct0);
    epilogue(v1, ct1);
  }
}

// ---------------- proj kernel: out = x @ Wo + bo ----------------
__global__ __launch_bounds__(128, 4) void proj(
  const unsigned short* __restrict__ xbuf, const unsigned short* __restrict__ Wof,
  const float* __restrict__ bo, float* __restrict__ out)
{
  const int t = threadIdx.x;
  const int lane = t & 63;
  const int w = t >> 6;
  const int lg = lane >> 4;
  const int lr = lane & 15;
  const int n0 = blockIdx.x * 32 + w * 16;
  const f4 z4 = {0.f, 0.f, 0.f, 0.f};
  const unsigned short* xr = xbuf + (size_t)(n0 + lr) * 256;
  const unsigned short* wob = Wof + (size_t)lane * 8;
  #pragma unroll
  for (int p = 0; p < 4; ++p){
    f4 oac[4] = {z4, z4, z4, z4};
    #pragma unroll
    for (int kt = 0; kt < 8; ++kt){
      s8 xf = *(const s8*)(xr + kt * 32 + lg * 8);
      #pragma unroll
      for (int ci = 0; ci < 4; ++ci)
        oac[ci] = MFMA16(xf, *(const s8*)(wob + (size_t)(kt * 16 + p * 4 + ci) * 512), oac[ci]);
    }
    #pragma unroll
    for (int ci = 0; ci < 4; ++ci){
      int c = (p * 4 + ci) * 16 + lr;
      float bov = bo[c];
      #pragma unroll
      for (int r = 0; r < 4; ++r)
        out[(size_t)(n0 + lg * 4 + r) * 256 + c] = oac[ci][r] + bov;
    }
  }
}

// ---------------- fallback monolithic kernel (R4, proven) ----------------
__global__ __launch_bounds__(256, 4) void attn_mono(
  const float* __restrict__ q, const float* __restrict__ k,
  const float* __restrict__ pos, const int* __restrict__ mask,
  const float* __restrict__ Wp1, const float* __restrict__ bp1,
  const float* __restrict__ bp2, const float* __restrict__ bo,
  const float* __restrict__ bh,
  const unsigned short* __restrict__ Ws2f, const unsigned short* __restrict__ WsWa1f,
  const unsigned short* __restrict__ Wp2f, const unsigned short* __restrict__ Wa2f,
  const unsigned short* __restrict__ Wp2Wa1f, const unsigned short* __restrict__ Wof,
  float* __restrict__ out)
{
  __shared__ unsigned short kA[16384];
  __shared__ unsigned short phL[2048];
  __shared__ unsigned short hL[2048];
  __shared__ unsigned short xT[4096];

  const int t = threadIdx.x;
  const int lane = t & 63;
  const int w = t >> 6;
  const int lg = lane >> 4;
  const int lr = lane & 15;
  const int bn0 = blockIdx.x * 4;
  const int n0 = bn0 + w;
  const f4 z4 = {0.f, 0.f, 0.f, 0.f};

  const float* krow = k + (size_t)n0 * 4096 + (size_t)lr * 256;
  const float* qrow = q + (size_t)n0 * 256;
  const unsigned short* wa1b = WsWa1f + (size_t)lane * 8;
  f4 khac[2] = {z4, z4};
  #pragma unroll
  for (int kt = 0; kt < 8; ++kt){
    int c0 = kt * 32 + lg * 8;
    f4 ka = *(const f4*)(krow + c0);
    f4 kb = *(const f4*)(krow + c0 + 4);
    f4 qa = *(const f4*)(qrow + c0);
    f4 qb = *(const f4*)(qrow + c0 + 4);
    s8 kf, mf;
    #pragma unroll
    for (int j = 0; j < 4; ++j){
      kf[j]     = (short)f2bf(ka[j]);
      kf[4 + j] = (short)f2bf(kb[j]);
      mf[j]     = (short)f2bf(ka[j] - qa[j]);
      mf[4 + j] = (short)f2bf(kb[j] - qb[j]);
    }
    *(s8*)(kA + ((w * 8 + kt) * 64 + lane) * 8) = kf;
    khac[0] = MFMA16(mf, *(const s8*)(wa1b + (size_t)(kt * 2 + 0) * 512), khac[0]);
    khac[1] = MFMA16(mf, *(const s8*)(wa1b + (size_t)(kt * 2 + 1) * 512), khac[1]);
  }
  s8 phfrag;
  {
    f4 pv = *(const f4*)(pos + (size_t)n0 * 64 + (size_t)lr * 4);
    f4 h0 = *(const f4*)(bp1 + lg * 8);
    f4 h1 = *(const f4*)(bp1 + lg * 8 + 4);
    #pragma unroll
    for (int p = 0; p < 4; ++p){
      f4 w0 = *(const f4*)(Wp1 + p * 32 + lg * 8);
      f4 w1 = *(const f4*)(Wp1 + p * 32 + lg * 8 + 4);
      #pragma unroll
      for (int j = 0; j < 4; ++j){ h0[j] += pv[p] * w0[j]; h1[j] += pv[p] * w1[j]; }
    }
    #pragma unroll
    for (int j = 0; j < 4; ++j){
      phfrag[j]     = (short)f2bf(fmaxf(h0[j], 0.f));
      phfrag[4 + j] = (short)f2bf(fmaxf(h1[j], 0.f));
    }
  }
  *(s8*)(phL + (w * 64 + lane) * 8) = phfrag;
  {
    const unsigned short* wpwb = Wp2Wa1f + (size_t)lane * 8;
    khac[0] = MFMA16(phfrag, *(const s8*)(wpwb), khac[0]);
    khac[1] = MFMA16(phfrag, *(const s8*)(wpwb + 512), khac[1]);
  }
  #pragma unroll
  for (int ct2 = 0; ct2 < 2; ++ct2){
    float bhc = bh[ct2 * 16 + lr];
    #pragma unroll
    for (int r = 0; r < 4; ++r){
      int m = lg * 4 + r, col = ct2 * 16 + lr;
      hL[w * 512 + ((col >> 3) * 16 + m) * 8 + (col & 7)] = f2bf(fmaxf(khac[ct2][r] + bhc, 0.f));
    }
  }
  __syncthreads();

  const unsigned short* ws2b = Ws2f + (size_t)lane * 8;
  const unsigned short* wp2b = Wp2f + (size_t)lane * 8;
  const unsigned short* wa2b = Wa2f + (size_t)lane * 8;
  #pragma unroll
  for (int ci = 0; ci < 4; ++ci){
    int ct = w * 4 + ci;
    f4 vacc[4] = {z4, z4, z4, z4};
    #pragma unroll
    for (int kt = 0; kt < 8; ++kt){
      s8 bw = *(const s8*)(ws2b + (size_t)(kt * 16 + ct) * 512);
      #pragma unroll
      for (int n = 0; n < 4; ++n){
        s8 af = *(const s8*)(kA + ((n * 8 + kt) * 64 + lane) * 8);
        vacc[n] = MFMA16(af, bw, vacc[n]);
      }
    }
    s8 bp = *(const s8*)(wp2b + (size_t)ct * 512);
    s8 ba = *(const s8*)(wa2b + (size_t)ct * 512);
    f4 pf[4], aa[4];
    #pragma unroll
    for (int n = 0; n < 4; ++n){
      s8 pfr = *(const s8*)(phL + (n * 64 + lane) * 8);
      s8 hfr = *(const s8*)(hL + (n * 64 + lane) * 8);
      pf[n] = MFMA16(pfr, bp, z4);
      aa[n] = MFMA16(hfr, ba, z4);
    }
    float bp2c = bp2[ct * 16 + lr];
    #pragma unroll
    for (int n = 0; n < 4; ++n){
      i4 mv = *(const i4*)(mask + (size_t)(bn0 + n) * 16 + lg * 4);
      float lg0 = mv[0] ? aa[n][0] : -1e9f;
      float lg1 = mv[1] ? aa[n][1] : -1e9f;
      float lg2 = mv[2] ? aa[n][2] : -1e9f;
      float lg3 = mv[3] ? aa[n][3] : -1e9f;
      float mx = fmaxf(fmaxf(lg0, lg1), fmaxf(lg2, lg3));
      mx = fmaxf(mx, __shfl_xor(mx, 16));
      mx = fmaxf(mx, __shfl_xor(mx, 32));
      float p0 = __expf(lg0 - mx), p1 = __expf(lg1 - mx);
      float p2 = __expf(lg2 - mx), p3 = __expf(lg3 - mx);
      float den = p0 + p1 + p2 + p3;
      float num = p0 * (vacc[n][0] + pf[n][0] + bp2c)
                + p1 * (vacc[n][1] + pf[n][1] + bp2c)
                + p2 * (vacc[n][2] + pf[n][2] + bp2c)
                + p3 * (vacc[n][3] + pf[n][3] + bp2c);
      den += __shfl_xor(den, 16); den += __shfl_xor(den, 32);
      num += __shfl_xor(num, 16); num += __shfl_xor(num, 32);
      if (lane < 16){
        int c = ct * 16 + lr;
        xT[((c >> 5) * 64 + ((c >> 3) & 3) * 16 + n) * 8 + (c & 7)] = f2bf(__fdividef(num, den));
      }
    }
  }
  __syncthreads();

  f4 oac[4] = {z4, z4, z4, z4};
  const unsigned short* wob = Wof + (size_t)lane * 8;
  #pragma unroll
  for (int kt = 0; kt < 8; ++kt){
    s8 xf = *(const s8*)(xT + (kt * 64 + lane) * 8);
    #pragma unroll
    for (int ci = 0; ci < 4; ++ci)
      oac[ci] = MFMA16(xf, *(const s8*)(wob + (size_t)(kt * 16 + w * 4 + ci) * 512), oac[ci]);
  }
  if (lane < 16){
    #pragma unroll
    for (int ci = 0; ci < 4; ++ci){
      int c = (w * 4 + ci) * 16 + lr;
      float bov = bo[c];
      #pragma unroll
      for (int r = 0; r < 4; ++r)
        out[(size_t)(bn0 + r) * 256 + c] = oac[ci][r] + bov;
    }
  }
}

extern "C" void kernel_launch(void* const* d_in, const int* in_sizes, int n_in,
                              void* d_out, int out_size, void* d_ws, size_t ws_size,
                              hipStream_t stream) {
  (void)in_sizes; (void)n_in; (void)out_size;
  const float* q   = (const float*)d_in[0];
  const float* k   = (const float*)d_in[1];
  const float* pos = (const float*)d_in[2];
  const int*   msk = (const int*)d_in[3];
  const float* Ws  = (const float*)d_in[4];
  const float* Wp1 = (const float*)d_in[5];
  const float* bp1 = (const float*)d_in[6];
  const float* Wp2 = (const float*)d_in[7];
  const float* bp2 = (const float*)d_in[8];
  const float* Wa1 = (const float*)d_in[9];
  const float* ba1 = (const float*)d_in[10];
  const float* Wa2 = (const float*)d_in[11];
  // d_in[12] = ba2: constant along softmax axis -> mathematically a no-op
  const float* Wo  = (const float*)d_in[13];
  const float* bo  = (const float*)d_in[14];

  if (ws_size < 313472) return;
  char* ws = (char*)d_ws;
  unsigned short* Ws2f    = (unsigned short*)(ws + 0);       // 131072 B
  unsigned short* Wof     = (unsigned short*)(ws + 131072);  // 131072 B
  unsigned short* WsWa1f  = (unsigned short*)(ws + 262144);  // 16384 B
  unsigned short* Wp2f    = (unsigned short*)(ws + 278528);  // 16384 B
  unsigned short* Wa2f    = (unsigned short*)(ws + 294912);  // 16384 B
  unsigned short* Wp2Wa1f = (unsigned short*)(ws + 311296);  // 2048 B
  float*          bh      = (float*)(ws + 313344);           // 128 B
  unsigned short* xbuf    = (unsigned short*)(ws + 313472);  // 8388608 B

  prep1<<<dim3(256), dim3(256), 0, stream>>>(Ws, Wa1, Wo, Ws2f, Wof, WsWa1f);
  prep2<<<dim3(64), dim3(256), 0, stream>>>(Wp2, Wa2, Wa1, bp2, ba1, Wp2f, Wa2f, Wp2Wa1f, bh);

  if (ws_size >= 313472 + 8388608) {
    attn_x<<<dim3(4096), dim3(256), 0, stream>>>(q, k, pos, msk, Wp1, bp1, bp2, bh,
                                                 Ws2f, WsWa1f, Wp2f, Wa2f, Wp2Wa1f, xbuf);
    proj<<<dim3(512), dim3(128), 0, stream>>>(xbuf, Wof, bo, (float*)d_out);
  } else {
    attn_mono<<<dim3(4096), dim3(256), 0, stream>>>(q, k, pos, msk, Wp1, bp1, bp2, bo, bh,
                                                    Ws2f, WsWa1f, Wp2f, Wa2f, Wp2Wa1f, Wof,
                                                    (float*)d_out);
  }
}

// Round 10
// 168.275 us; speedup vs baseline: 1.2837x; 1.0949x over previous
//
#include <hip/hip_runtime.h>
#include <hip/hip_bf16.h>

typedef __attribute__((ext_vector_type(4))) float f4;
typedef __attribute__((ext_vector_type(4))) int i4;
typedef __attribute__((ext_vector_type(8))) short s8;

#define MFMA16(a,b,c) __builtin_amdgcn_mfma_f32_16x16x32_bf16((a),(b),(c),0,0,0)

static __device__ __forceinline__ unsigned short f2bf(float x){
  return __builtin_bit_cast(unsigned short, __float2bfloat16(x));
}
// B-fragment-linear index for mfma_f32_16x16x32_bf16:
// lane l holds B[k = kt*32 + (l>>4)*8 + j][col = ct*16 + (l&15)], j=0..7
__device__ __forceinline__ int fidx(int kk, int c, int nct){
  return ((((kk >> 5) * nct + (c >> 4)) << 6) + (((kk >> 3) & 3) * 16 + (c & 15))) * 8 + (kk & 7);
}

// ---------------- prep kernels ----------------
__global__ void prep1(const float* __restrict__ Ws, const float* __restrict__ Wa1,
                      const float* __restrict__ Wo,
                      unsigned short* __restrict__ Ws2f, unsigned short* __restrict__ Wof,
                      unsigned short* __restrict__ WsWa1f){
  __shared__ float wrow[256];
  int i = blockIdx.x, t = threadIdx.x;
  wrow[t] = Ws[i*256 + t];
  __syncthreads();
  float a1 = 0.f;
  for (int t2 = 0; t2 < 256; ++t2) a1 += wrow[t2] * Ws[t2*256 + t];   // Ws2 = Ws@Ws
  Ws2f[fidx(i, t, 16)] = f2bf(a1);
  Wof[fidx(i, t, 16)]  = f2bf(Wo[i*256 + t]);
  if (t < 32){
    float a2 = 0.f;
    for (int t2 = 0; t2 < 256; ++t2) a2 += wrow[t2] * Wa1[t2*32 + t]; // WsWa1 = Ws@Wa1
    WsWa1f[fidx(i, t, 2)] = f2bf(a2);
  }
}

// 64 blocks x 256 threads (parallelized)
__global__ void prep2(const float* __restrict__ Wp2, const float* __restrict__ Wa2,
                      const float* __restrict__ Wa1, const float* __restrict__ bp2,
                      const float* __restrict__ ba1,
                      unsigned short* __restrict__ Wp2f, unsigned short* __restrict__ Wa2f,
                      unsigned short* __restrict__ Wp2Wa1f, float* __restrict__ bh){
  int gid = blockIdx.x * 256 + threadIdx.x;   // 0..16383
  if (gid < 8192){
    int kk = gid >> 8, c = gid & 255;
    Wp2f[fidx(kk, c, 16)] = f2bf(Wp2[gid]);
  } else {
    int g = gid - 8192; int kk = g >> 8, c = g & 255;
    Wa2f[fidx(kk, c, 16)] = f2bf(Wa2[g]);
  }
  if (gid < 1024){                     // Wp2Wa1 = Wp2@Wa1 [32][32]
    int h1 = gid >> 5, h2 = gid & 31;
    float a = 0.f;
    for (int c = 0; c < 256; ++c) a += Wp2[h1*256 + c] * Wa1[c*32 + h2];
    Wp2Wa1f[fidx(h1, h2, 2)] = f2bf(a);
  }
  if (gid < 32){                       // bh = bp2@Wa1 + ba1
    float a = ba1[gid];
    for (int c = 0; c < 256; ++c) a += bp2[c] * Wa1[c*32 + gid];
    bh[gid] = a;
  }
}

// ---------------- main kernel: phases B..E, x -> global bf16 ----------------
// Block = 4 n-rows. Phase B row-split (wave w <-> n w), phase E column-split
// (wave w <-> cols [64w,64w+64)) with ci-PAIRING via NAMED accumulators
// (no lambda, no array-pointer args -- R9 lesson: pointer-to-local defeats
// SROA and sends the accumulators to scratch). ONE barrier.
__global__ __launch_bounds__(256, 4) void attn_x(
  const float* __restrict__ q, const float* __restrict__ k,
  const float* __restrict__ pos, const int* __restrict__ mask,
  const float* __restrict__ Wp1, const float* __restrict__ bp1,
  const float* __restrict__ bp2, const float* __restrict__ bh,
  const unsigned short* __restrict__ Ws2f, const unsigned short* __restrict__ WsWa1f,
  const unsigned short* __restrict__ Wp2f, const unsigned short* __restrict__ Wa2f,
  const unsigned short* __restrict__ Wp2Wa1f,
  unsigned short* __restrict__ xbuf)
{
  __shared__ unsigned short kA[16384];  // 32 KB: [n][kt][lane][8] bf16 A-frags of k
  __shared__ unsigned short phL[2048];  // 4 KB:  [n][lane][8] pos-hidden A-frags
  __shared__ unsigned short hL[2048];   // 4 KB:  [n][lane][8] attn-hidden A-frags

  const int t = threadIdx.x;
  const int lane = t & 63;
  const int w = t >> 6;
  const int lg = lane >> 4;
  const int lr = lane & 15;
  const int bn0 = blockIdx.x * 4;
  const int n0 = bn0 + w;
  const f4 z4 = {0.f, 0.f, 0.f, 0.f};

  // ---- Phase B: per-kt {k,q loads, convert, kA write, kh MFMAs}
  const float* krow = k + (size_t)n0 * 4096 + (size_t)lr * 256;
  const float* qrow = q + (size_t)n0 * 256;
  const unsigned short* wa1b = WsWa1f + (size_t)lane * 8;
  f4 khac[2] = {z4, z4};
  #pragma unroll
  for (int kt = 0; kt < 8; ++kt){
    int c0 = kt * 32 + lg * 8;
    f4 ka = *(const f4*)(krow + c0);
    f4 kb = *(const f4*)(krow + c0 + 4);
    f4 qa = *(const f4*)(qrow + c0);
    f4 qb = *(const f4*)(qrow + c0 + 4);
    s8 kf, mf;
    #pragma unroll
    for (int j = 0; j < 4; ++j){
      kf[j]     = (short)f2bf(ka[j]);
      kf[4 + j] = (short)f2bf(kb[j]);
      mf[j]     = (short)f2bf(ka[j] - qa[j]);
      mf[4 + j] = (short)f2bf(kb[j] - qb[j]);
    }
    *(s8*)(kA + ((w * 8 + kt) * 64 + lane) * 8) = kf;
    khac[0] = MFMA16(mf, *(const s8*)(wa1b + (size_t)(kt * 2 + 0) * 512), khac[0]);
    khac[1] = MFMA16(mf, *(const s8*)(wa1b + (size_t)(kt * 2 + 1) * 512), khac[1]);
  }

  // pos-MLP per-lane directly in A-frag layout
  s8 phfrag;
  {
    f4 pv = *(const f4*)(pos + (size_t)n0 * 64 + (size_t)lr * 4);
    f4 h0 = *(const f4*)(bp1 + lg * 8);
    f4 h1 = *(const f4*)(bp1 + lg * 8 + 4);
    #pragma unroll
    for (int p = 0; p < 4; ++p){
      f4 w0 = *(const f4*)(Wp1 + p * 32 + lg * 8);
      f4 w1 = *(const f4*)(Wp1 + p * 32 + lg * 8 + 4);
      #pragma unroll
      for (int j = 0; j < 4; ++j){ h0[j] += pv[p] * w0[j]; h1[j] += pv[p] * w1[j]; }
    }
    #pragma unroll
    for (int j = 0; j < 4; ++j){
      phfrag[j]     = (short)f2bf(fmaxf(h0[j], 0.f));
      phfrag[4 + j] = (short)f2bf(fmaxf(h1[j], 0.f));
    }
  }
  *(s8*)(phL + (w * 64 + lane) * 8) = phfrag;

  // khac += ph@Wp2Wa1
  {
    const unsigned short* wpwb = Wp2Wa1f + (size_t)lane * 8;
    khac[0] = MFMA16(phfrag, *(const s8*)(wpwb), khac[0]);
    khac[1] = MFMA16(phfrag, *(const s8*)(wpwb + 512), khac[1]);
  }

  // h = relu(khac + bh) scattered into hL A-frag slots
  #pragma unroll
  for (int ct2 = 0; ct2 < 2; ++ct2){
    float bhc = bh[ct2 * 16 + lr];
    #pragma unroll
    for (int r = 0; r < 4; ++r){
      int m = lg * 4 + r, col = ct2 * 16 + lr;
      hL[w * 512 + ((col >> 3) * 16 + m) * 8 + (col & 7)] = f2bf(fmaxf(khac[ct2][r] + bhc, 0.f));
    }
  }
  __syncthreads();

  // ---- Phase E: column-split with ci-pairs, NAMED accumulators, macro epilogue.
  const unsigned short* ws2b = Ws2f + (size_t)lane * 8;
  const unsigned short* wp2b = Wp2f + (size_t)lane * 8;
  const unsigned short* wa2b = Wa2f + (size_t)lane * 8;

#define EPI_N(VN, N, CT, BP, BA, BP2C) { \
    s8 pfr = *(const s8*)(phL + ((N) * 64 + lane) * 8); \
    s8 hfr = *(const s8*)(hL + ((N) * 64 + lane) * 8); \
    f4 pf = MFMA16(pfr, (BP), z4); \
    f4 aa = MFMA16(hfr, (BA), z4); \
    i4 mv = *(const i4*)(mask + (size_t)(bn0 + (N)) * 16 + lg * 4); \
    float lg0 = mv[0] ? aa[0] : -1e9f; \
    float lg1 = mv[1] ? aa[1] : -1e9f; \
    float lg2 = mv[2] ? aa[2] : -1e9f; \
    float lg3 = mv[3] ? aa[3] : -1e9f; \
    float mx = fmaxf(fmaxf(lg0, lg1), fmaxf(lg2, lg3)); \
    mx = fmaxf(mx, __shfl_xor(mx, 16)); \
    mx = fmaxf(mx, __shfl_xor(mx, 32)); \
    float p0 = __expf(lg0 - mx), p1 = __expf(lg1 - mx); \
    float p2 = __expf(lg2 - mx), p3 = __expf(lg3 - mx); \
    float den = p0 + p1 + p2 + p3; \
    float num = p0 * ((VN)[0] + pf[0] + (BP2C)) \
              + p1 * ((VN)[1] + pf[1] + (BP2C)) \
              + p2 * ((VN)[2] + pf[2] + (BP2C)) \
              + p3 * ((VN)[3] + pf[3] + (BP2C)); \
    den += __shfl_xor(den, 16); den += __shfl_xor(den, 32); \
    num += __shfl_xor(num, 16); num += __shfl_xor(num, 32); \
    if (lane < 16) \
      xbuf[(size_t)(bn0 + (N)) * 256 + (CT) * 16 + lr] = f2bf(__fdividef(num, den)); \
  }

#define EPILOGUE(V0, V1, V2, V3, CT) { \
    s8 bp = *(const s8*)(wp2b + (size_t)(CT) * 512); \
    s8 ba = *(const s8*)(wa2b + (size_t)(CT) * 512); \
    float bp2c = bp2[(CT) * 16 + lr]; \
    EPI_N(V0, 0, CT, bp, ba, bp2c); \
    EPI_N(V1, 1, CT, bp, ba, bp2c); \
    EPI_N(V2, 2, CT, bp, ba, bp2c); \
    EPI_N(V3, 3, CT, bp, ba, bp2c); \
  }

  #pragma unroll
  for (int cp = 0; cp < 2; ++cp){
    const int ct0 = w * 4 + cp * 2;
    const int ct1 = ct0 + 1;
    f4 v00 = z4, v01 = z4, v02 = z4, v03 = z4;   // ct0, n=0..3
    f4 v10 = z4, v11 = z4, v12 = z4, v13 = z4;   // ct1, n=0..3
    #pragma unroll
    for (int kt = 0; kt < 8; ++kt){
      s8 b0 = *(const s8*)(ws2b + (size_t)(kt * 16 + ct0) * 512);
      s8 b1 = *(const s8*)(ws2b + (size_t)(kt * 16 + ct1) * 512);
      s8 af0 = *(const s8*)(kA + ((0 * 8 + kt) * 64 + lane) * 8);
      s8 af1 = *(const s8*)(kA + ((1 * 8 + kt) * 64 + lane) * 8);
      s8 af2 = *(const s8*)(kA + ((2 * 8 + kt) * 64 + lane) * 8);
      s8 af3 = *(const s8*)(kA + ((3 * 8 + kt) * 64 + lane) * 8);
      v00 = MFMA16(af0, b0, v00); v10 = MFMA16(af0, b1, v10);
      v01 = MFMA16(af1, b0, v01); v11 = MFMA16(af1, b1, v11);
      v02 = MFMA16(af2, b0, v02); v12 = MFMA16(af2, b1, v12);
      v03 = MFMA16(af3, b0, v03); v13 = MFMA16(af3, b1, v13);
    }
    EPILOGUE(v00, v01, v02, v03, ct0);
    EPILOGUE(v10, v11, v12, v13, ct1);
  }
#undef EPILOGUE
#undef EPI_N
}

// ---------------- proj kernel: out = x @ Wo + bo ----------------
__global__ __launch_bounds__(128, 4) void proj(
  const unsigned short* __restrict__ xbuf, const unsigned short* __restrict__ Wof,
  const float* __restrict__ bo, float* __restrict__ out)
{
  const int t = threadIdx.x;
  const int lane = t & 63;
  const int w = t >> 6;
  const int lg = lane >> 4;
  const int lr = lane & 15;
  const int n0 = blockIdx.x * 32 + w * 16;
  const f4 z4 = {0.f, 0.f, 0.f, 0.f};
  const unsigned short* xr = xbuf + (size_t)(n0 + lr) * 256;
  const unsigned short* wob = Wof + (size_t)lane * 8;
  #pragma unroll
  for (int p = 0; p < 4; ++p){
    f4 oac[4] = {z4, z4, z4, z4};
    #pragma unroll
    for (int kt = 0; kt < 8; ++kt){
      s8 xf = *(const s8*)(xr + kt * 32 + lg * 8);
      #pragma unroll
      for (int ci = 0; ci < 4; ++ci)
        oac[ci] = MFMA16(xf, *(const s8*)(wob + (size_t)(kt * 16 + p * 4 + ci) * 512), oac[ci]);
    }
    #pragma unroll
    for (int ci = 0; ci < 4; ++ci){
      int c = (p * 4 + ci) * 16 + lr;
      float bov = bo[c];
      #pragma unroll
      for (int r = 0; r < 4; ++r)
        out[(size_t)(n0 + lg * 4 + r) * 256 + c] = oac[ci][r] + bov;
    }
  }
}

// ---------------- fallback monolithic kernel (R4, proven) ----------------
__global__ __launch_bounds__(256, 4) void attn_mono(
  const float* __restrict__ q, const float* __restrict__ k,
  const float* __restrict__ pos, const int* __restrict__ mask,
  const float* __restrict__ Wp1, const float* __restrict__ bp1,
  const float* __restrict__ bp2, const float* __restrict__ bo,
  const float* __restrict__ bh,
  const unsigned short* __restrict__ Ws2f, const unsigned short* __restrict__ WsWa1f,
  const unsigned short* __restrict__ Wp2f, const unsigned short* __restrict__ Wa2f,
  const unsigned short* __restrict__ Wp2Wa1f, const unsigned short* __restrict__ Wof,
  float* __restrict__ out)
{
  __shared__ unsigned short kA[16384];
  __shared__ unsigned short phL[2048];
  __shared__ unsigned short hL[2048];
  __shared__ unsigned short xT[4096];

  const int t = threadIdx.x;
  const int lane = t & 63;
  const int w = t >> 6;
  const int lg = lane >> 4;
  const int lr = lane & 15;
  const int bn0 = blockIdx.x * 4;
  const int n0 = bn0 + w;
  const f4 z4 = {0.f, 0.f, 0.f, 0.f};

  const float* krow = k + (size_t)n0 * 4096 + (size_t)lr * 256;
  const float* qrow = q + (size_t)n0 * 256;
  const unsigned short* wa1b = WsWa1f + (size_t)lane * 8;
  f4 khac[2] = {z4, z4};
  #pragma unroll
  for (int kt = 0; kt < 8; ++kt){
    int c0 = kt * 32 + lg * 8;
    f4 ka = *(const f4*)(krow + c0);
    f4 kb = *(const f4*)(krow + c0 + 4);
    f4 qa = *(const f4*)(qrow + c0);
    f4 qb = *(const f4*)(qrow + c0 + 4);
    s8 kf, mf;
    #pragma unroll
    for (int j = 0; j < 4; ++j){
      kf[j]     = (short)f2bf(ka[j]);
      kf[4 + j] = (short)f2bf(kb[j]);
      mf[j]     = (short)f2bf(ka[j] - qa[j]);
      mf[4 + j] = (short)f2bf(kb[j] - qb[j]);
    }
    *(s8*)(kA + ((w * 8 + kt) * 64 + lane) * 8) = kf;
    khac[0] = MFMA16(mf, *(const s8*)(wa1b + (size_t)(kt * 2 + 0) * 512), khac[0]);
    khac[1] = MFMA16(mf, *(const s8*)(wa1b + (size_t)(kt * 2 + 1) * 512), khac[1]);
  }
  s8 phfrag;
  {
    f4 pv = *(const f4*)(pos + (size_t)n0 * 64 + (size_t)lr * 4);
    f4 h0 = *(const f4*)(bp1 + lg * 8);
    f4 h1 = *(const f4*)(bp1 + lg * 8 + 4);
    #pragma unroll
    for (int p = 0; p < 4; ++p){
      f4 w0 = *(const f4*)(Wp1 + p * 32 + lg * 8);
      f4 w1 = *(const f4*)(Wp1 + p * 32 + lg * 8 + 4);
      #pragma unroll
      for (int j = 0; j < 4; ++j){ h0[j] += pv[p] * w0[j]; h1[j] += pv[p] * w1[j]; }
    }
    #pragma unroll
    for (int j = 0; j < 4; ++j){
      phfrag[j]     = (short)f2bf(fmaxf(h0[j], 0.f));
      phfrag[4 + j] = (short)f2bf(fmaxf(h1[j], 0.f));
    }
  }
  *(s8*)(phL + (w * 64 + lane) * 8) = phfrag;
  {
    const unsigned short* wpwb = Wp2Wa1f + (size_t)lane * 8;
    khac[0] = MFMA16(phfrag, *(const s8*)(wpwb), khac[0]);
    khac[1] = MFMA16(phfrag, *(const s8*)(wpwb + 512), khac[1]);
  }
  #pragma unroll
  for (int ct2 = 0; ct2 < 2; ++ct2){
    float bhc = bh[ct2 * 16 + lr];
    #pragma unroll
    for (int r = 0; r < 4; ++r){
      int m = lg * 4 + r, col = ct2 * 16 + lr;
      hL[w * 512 + ((col >> 3) * 16 + m) * 8 + (col & 7)] = f2bf(fmaxf(khac[ct2][r] + bhc, 0.f));
    }
  }
  __syncthreads();

  const unsigned short* ws2b = Ws2f + (size_t)lane * 8;
  const unsigned short* wp2b = Wp2f + (size_t)lane * 8;
  const unsigned short* wa2b = Wa2f + (size_t)lane * 8;
  #pragma unroll
  for (int ci = 0; ci < 4; ++ci){
    int ct = w * 4 + ci;
    f4 vacc[4] = {z4, z4, z4, z4};
    #pragma unroll
    for (int kt = 0; kt < 8; ++kt){
      s8 bw = *(const s8*)(ws2b + (size_t)(kt * 16 + ct) * 512);
      #pragma unroll
      for (int n = 0; n < 4; ++n){
        s8 af = *(const s8*)(kA + ((n * 8 + kt) * 64 + lane) * 8);
        vacc[n] = MFMA16(af, bw, vacc[n]);
      }
    }
    s8 bp = *(const s8*)(wp2b + (size_t)ct * 512);
    s8 ba = *(const s8*)(wa2b + (size_t)ct * 512);
    f4 pf[4], aa[4];
    #pragma unroll
    for (int n = 0; n < 4; ++n){
      s8 pfr = *(const s8*)(phL + (n * 64 + lane) * 8);
      s8 hfr = *(const s8*)(hL + (n * 64 + lane) * 8);
      pf[n] = MFMA16(pfr, bp, z4);
      aa[n] = MFMA16(hfr, ba, z4);
    }
    float bp2c = bp2[ct * 16 + lr];
    #pragma unroll
    for (int n = 0; n < 4; ++n){
      i4 mv = *(const i4*)(mask + (size_t)(bn0 + n) * 16 + lg * 4);
      float lg0 = mv[0] ? aa[n][0] : -1e9f;
      float lg1 = mv[1] ? aa[n][1] : -1e9f;
      float lg2 = mv[2] ? aa[n][2] : -1e9f;
      float lg3 = mv[3] ? aa[n][3] : -1e9f;
      float mx = fmaxf(fmaxf(lg0, lg1), fmaxf(lg2, lg3));
      mx = fmaxf(mx, __shfl_xor(mx, 16));
      mx = fmaxf(mx, __shfl_xor(mx, 32));
      float p0 = __expf(lg0 - mx), p1 = __expf(lg1 - mx);
      float p2 = __expf(lg2 - mx), p3 = __expf(lg3 - mx);
      float den = p0 + p1 + p2 + p3;
      float num = p0 * (vacc[n][0] + pf[n][0] + bp2c)
                + p1 * (vacc[n][1] + pf[n][1] + bp2c)
                + p2 * (vacc[n][2] + pf[n][2] + bp2c)
                + p3 * (vacc[n][3] + pf[n][3] + bp2c);
      den += __shfl_xor(den, 16); den += __shfl_xor(den, 32);
      num += __shfl_xor(num, 16); num += __shfl_xor(num, 32);
      if (lane < 16){
        int c = ct * 16 + lr;
        xT[((c >> 5) * 64 + ((c >> 3) & 3) * 16 + n) * 8 + (c & 7)] = f2bf(__fdividef(num, den));
      }
    }
  }
  __syncthreads();

  f4 oac[4] = {z4, z4, z4, z4};
  const unsigned short* wob = Wof + (size_t)lane * 8;
  #pragma unroll
  for (int kt = 0; kt < 8; ++kt){
    s8 xf = *(const s8*)(xT + (kt * 64 + lane) * 8);
    #pragma unroll
    for (int ci = 0; ci < 4; ++ci)
      oac[ci] = MFMA16(xf, *(const s8*)(wob + (size_t)(kt * 16 + w * 4 + ci) * 512), oac[ci]);
  }
  if (lane < 16){
    #pragma unroll
    for (int ci = 0; ci < 4; ++ci){
      int c = (w * 4 + ci) * 16 + lr;
      float bov = bo[c];
      #pragma unroll
      for (int r = 0; r < 4; ++r)
        out[(size_t)(bn0 + r) * 256 + c] = oac[ci][r] + bov;
    }
  }
}

extern "C" void kernel_launch(void* const* d_in, const int* in_sizes, int n_in,
                              void* d_out, int out_size, void* d_ws, size_t ws_size,
                              hipStream_t stream) {
  (void)in_sizes; (void)n_in; (void)out_size;
  const float* q   = (const float*)d_in[0];
  const float* k   = (const float*)d_in[1];
  const float* pos = (const float*)d_in[2];
  const int*   msk = (const int*)d_in[3];
  const float* Ws  = (const float*)d_in[4];
  const float* Wp1 = (const float*)d_in[5];
  const float* bp1 = (const float*)d_in[6];
  const float* Wp2 = (const float*)d_in[7];
  const float* bp2 = (const float*)d_in[8];
  const float* Wa1 = (const float*)d_in[9];
  const float* ba1 = (const float*)d_in[10];
  const float* Wa2 = (const float*)d_in[11];
  // d_in[12] = ba2: constant along softmax axis -> mathematically a no-op
  const float* Wo  = (const float*)d_in[13];
  const float* bo  = (const float*)d_in[14];

  if (ws_size < 313472) return;
  char* ws = (char*)d_ws;
  unsigned short* Ws2f    = (unsigned short*)(ws + 0);       // 131072 B
  unsigned short* Wof     = (unsigned short*)(ws + 131072);  // 131072 B
  unsigned short* WsWa1f  = (unsigned short*)(ws + 262144);  // 16384 B
  unsigned short* Wp2f    = (unsigned short*)(ws + 278528);  // 16384 B
  unsigned short* Wa2f    = (unsigned short*)(ws + 294912);  // 16384 B
  unsigned short* Wp2Wa1f = (unsigned short*)(ws + 311296);  // 2048 B
  float*          bh      = (float*)(ws + 313344);           // 128 B
  unsigned short* xbuf    = (unsigned short*)(ws + 313472);  // 8388608 B

  prep1<<<dim3(256), dim3(256), 0, stream>>>(Ws, Wa1, Wo, Ws2f, Wof, WsWa1f);
  prep2<<<dim3(64), dim3(256), 0, stream>>>(Wp2, Wa2, Wa1, bp2, ba1, Wp2f, Wa2f, Wp2Wa1f, bh);

  if (ws_size >= 313472 + 8388608) {
    attn_x<<<dim3(4096), dim3(256), 0, stream>>>(q, k, pos, msk, Wp1, bp1, bp2, bh,
                                                 Ws2f, WsWa1f, Wp2f, Wa2f, Wp2Wa1f, xbuf);
    proj<<<dim3(512), dim3(128), 0, stream>>>(xbuf, Wof, bo, (float*)d_out);
  } else {
    attn_mono<<<dim3(4096), dim3(256), 0, stream>>>(q, k, pos, msk, Wp1, bp1, bp2, bo, bh,
                                                    Ws2f, WsWa1f, Wp2f, Wa2f, Wp2Wa1f, Wof,
                                                    (float*)d_out);
  }
}